// Round 8
// baseline (202.899 us; speedup 1.0000x reference)
//
#include <hip/hip_runtime.h>
#include <hip/hip_bf16.h>

// SO3TensorProductLayer: out = relu(128*(x (x) x) @ W1 + b1) @ W2 + b2
// h[c][b] = 128 * sum_i x[b,i] * (sum_j W1T[c][i*128+j] * x[b,j])
// gemm1 v4: A = W1 packed in MFMA-fragment order, global->VGPR depth-2 ring
// (guarded prefetch), no K-loop barrier. Wave tile c32 x b128 (tm=2, tn=8).
// REGALLOC HISTORY (load-bearing):
//   r4: default bounds, tn=4 -> VGPR 212, NO spill (WRITE == Pb exactly)
//   r5: (256,4) cap 128 on fat body -> catastrophic spill (2 GB traffic)
//   r7: (256,2) cap 128ish -> VGPR pinned at 128 + ~96 B/thread K-loop spill
//       (WRITE 28.1 MB vs 16.8 Pb) -> MfmaUtil stuck 33% at any occupancy
// => Use DEFAULT bounds here. Grid 512 blocks = 2 blocks/CU fixes occupancy
//    by construction; allocator gets 256-reg headroom, acc stays in VGPRs,
//    fold is plain v_fmac, no scratch.
// Partials bf16 [z][b][c] (r4-proven).

typedef __attribute__((ext_vector_type(8))) short short8;   // 8 bf16
typedef __attribute__((ext_vector_type(4))) float floatx4;  // 4 fp32

__device__ __forceinline__ unsigned short f2bf(float f) {
    union { float f; unsigned int u; } v; v.f = f;
    unsigned int r = v.u + 0x7fffu + ((v.u >> 16) & 1u);   // RNE
    return (unsigned short)(r >> 16);
}
__device__ __forceinline__ float bf2f(unsigned short b) {
    union { unsigned int u; float f; } v; v.u = ((unsigned int)b) << 16;
    return v.f;
}

// ---------------------------------------------------------------------------
// Pack W1 [16384 K][512 C] fp32 -> W1Tp chunks of 1KB: chunk(c16,kc) holds
// A-fragment for c rows c16*16..+15, K cols kc*32..+31: wave load at
// (chunkBase + lane*16B) gives lane(m=lane&15,quad=lane>>4) the 8 bf16 of
// W1[K=kc*32+quad*8+j][c=c16*16+m].
__global__ __launch_bounds__(256) void pack_w1_kernel(
    const float* __restrict__ W1, unsigned short* __restrict__ W1Tp) {
    __shared__ float tile[64][65];
    const int k0 = blockIdx.x * 64;
    const int c0 = blockIdx.y * 64;
    const int tr = threadIdx.x >> 4;
    const int tc4 = (threadIdx.x & 15) * 4;
#pragma unroll
    for (int p = 0; p < 4; ++p) {
        int k = p * 16 + tr;
        float4 v = *(const float4*)(W1 + (long)(k0 + k) * 512 + c0 + tc4);
        tile[k][tc4 + 0] = v.x; tile[k][tc4 + 1] = v.y;
        tile[k][tc4 + 2] = v.z; tile[k][tc4 + 3] = v.w;
    }
    __syncthreads();
    const int lane = threadIdx.x & 63;
    const int w = threadIdx.x >> 6;
    const int m = lane & 15, quad = lane >> 4;
#pragma unroll
    for (int pass = 0; pass < 2; ++pass) {
        int chunk = w * 2 + pass;              // 0..7
        int kcL = chunk & 1, c16L = chunk >> 1;
        union { unsigned short s[8]; uint4 u; } o;
#pragma unroll
        for (int j = 0; j < 8; ++j)
            o.s[j] = f2bf(tile[kcL * 32 + quad * 8 + j][c16L * 16 + m]);
        long c16g = (c0 >> 4) + c16L;
        long kcg  = (k0 >> 5) + kcL;
        *(uint4*)(W1Tp + (c16g * 512 + kcg) * 512 + lane * 8) = o.u;
    }
}

// in: [R][C] fp32 -> out: [C][R] bf16 (for W2 -> W2T).
__global__ __launch_bounds__(256) void transpose_cast_kernel(
    const float* __restrict__ in, unsigned short* __restrict__ out, int R, int C) {
    __shared__ float tile[64][65];
    const int r0 = blockIdx.x * 64, c0 = blockIdx.y * 64;
    const int tr = threadIdx.x >> 4;
    const int tc4 = (threadIdx.x & 15) * 4;
#pragma unroll
    for (int p = 0; p < 4; ++p) {
        int r = p * 16 + tr;
        float4 v = *(const float4*)(in + (long)(r0 + r) * C + c0 + tc4);
        tile[r][tc4 + 0] = v.x; tile[r][tc4 + 1] = v.y;
        tile[r][tc4 + 2] = v.z; tile[r][tc4 + 3] = v.w;
    }
    __syncthreads();
#pragma unroll
    for (int p = 0; p < 4; ++p) {
        int c = p * 16 + tr;
        union { unsigned short s[4]; uint2 u; } pk;
#pragma unroll
        for (int e = 0; e < 4; ++e) pk.s[e] = f2bf(tile[tc4 + e][c]);
        *(uint2*)(out + (long)(c0 + c) * R + r0 + tc4) = pk.u;
    }
}

// ---------------------------------------------------------------------------
// gemm1 v4: Pb[z][b][c] (bf16) over i-chunk z. 256 thr = 4 waves (2wm c x
// 2wn b); wave tile c32 x b128 (tm=2, tn=8); block tile c64 x b256.
// grid (16 b, 8 c, 4 z) = 512 blocks = 2 blocks/CU, b fastest.
__global__ __launch_bounds__(256) void gemm1_kernel(
    const float* __restrict__ x,               // [4096][128]
    const unsigned short* __restrict__ W1Tp,
    unsigned short* __restrict__ Pb) {         // [4][4096][512] bf16
    __shared__ float xT[256][34];              // [b_local][i_local]; conflict-free
    const int tid = threadIdx.x;
    const int b0 = blockIdx.x * 256;
    const int c0 = blockIdx.y * 64;
    const int zi = blockIdx.z;
    const int i0 = zi * 32;

    // stage xT[b][i] (fold multipliers), coalesced global reads
    for (int idx = tid; idx < 256 * 32; idx += 256) {
        int bL = idx >> 5, iL = idx & 31;
        xT[bL][iL] = x[(long)(b0 + bL) * 128 + i0 + iL];
    }
    __syncthreads();

    const int wid = tid >> 6;
    const int wm = wid >> 1, wn = wid & 1;
    const int lane = tid & 63;
    const int n16 = lane & 15, quad = lane >> 4;
    const int bBase = b0 + wn * 128;
    const int c16base = (c0 >> 4) + wm * 2;
    const int bLloc = wn * 128 + n16;          // xT row for tn=0

    floatx4 acc[2][8];
#pragma unroll
    for (int tm = 0; tm < 2; ++tm)
#pragma unroll
        for (int tn = 0; tn < 8; ++tn) acc[tm][tn] = (floatx4){0.f, 0.f, 0.f, 0.f};
    const floatx4 zero4 = (floatx4){0.f, 0.f, 0.f, 0.f};

#pragma unroll
    for (int jh = 0; jh < 2; ++jh) {
        // x B-fragments, register-resident for this j-half (64 VGPRs)
        short8 Xf[2][8];
#pragma unroll
        for (int ks = 0; ks < 2; ++ks)
#pragma unroll
            for (int tn = 0; tn < 8; ++tn) {
                const float* xp = x + (long)(bBase + tn * 16 + n16) * 128
                                    + jh * 64 + ks * 32 + quad * 8;
                float4 v0 = *(const float4*)xp;
                float4 v1 = *(const float4*)(xp + 4);
                short8 f;
                f[0] = (short)f2bf(v0.x); f[1] = (short)f2bf(v0.y);
                f[2] = (short)f2bf(v0.z); f[3] = (short)f2bf(v0.w);
                f[4] = (short)f2bf(v1.x); f[5] = (short)f2bf(v1.y);
                f[6] = (short)f2bf(v1.z); f[7] = (short)f2bf(v1.w);
                Xf[ks][tn] = f;
            }
        // A chunk base pointers; per-i advance = 4 chunks = 2048 u16
        const unsigned short* aBase[2][2];
#pragma unroll
        for (int tm = 0; tm < 2; ++tm)
#pragma unroll
            for (int ks = 0; ks < 2; ++ks)
                aBase[tm][ks] = W1Tp
                    + ((long)(c16base + tm) * 512 + (long)i0 * 4 + jh * 2 + ks) * 512
                    + lane * 8;

        short8 Abuf[2][2][2];                  // [stage][tm][ks] depth-2 ring
#pragma unroll
        for (int tm = 0; tm < 2; ++tm)
#pragma unroll
            for (int ks = 0; ks < 2; ++ks) {
                Abuf[0][tm][ks] = *(const short8*)(aBase[tm][ks]);
                Abuf[1][tm][ks] = *(const short8*)(aBase[tm][ks] + 2048);
            }

#pragma unroll 2
        for (int i = 0; i < 32; ++i) {
            const int st = i & 1;
            float xi[8];                       // scalarized under unroll (no addr-taken)
#pragma unroll
            for (int tn = 0; tn < 8; ++tn)
                xi[tn] = xT[bLloc + tn * 16][i];
#pragma unroll
            for (int tm = 0; tm < 2; ++tm)
#pragma unroll
                for (int tn = 0; tn < 8; ++tn) {
                    floatx4 t = __builtin_amdgcn_mfma_f32_16x16x32_bf16(
                        Abuf[st][tm][0], Xf[0][tn], zero4, 0, 0, 0);
                    t = __builtin_amdgcn_mfma_f32_16x16x32_bf16(
                        Abuf[st][tm][1], Xf[1][tn], t, 0, 0, 0);
                    acc[tm][tn] += xi[tn] * t;
                }
            if (i < 30) {                      // guarded prefetch: no dead loads
#pragma unroll
                for (int tm = 0; tm < 2; ++tm)
#pragma unroll
                    for (int ks = 0; ks < 2; ++ks)
                        Abuf[st][tm][ks] =
                            *(const short8*)(aBase[tm][ks] + (long)(i + 2) * 2048);
            }
        }
    }

    // store bf16 partial in [z][b][c]: per (tm,tn) lane owns 4 c-consecutive
    unsigned short* pb = Pb + (long)zi * (4096L * 512);
#pragma unroll
    for (int tm = 0; tm < 2; ++tm)
#pragma unroll
        for (int tn = 0; tn < 8; ++tn) {
            int b = bBase + tn * 16 + n16;
            int cb = (c16base + tm) * 16 + quad * 4;
            union { unsigned short s[4]; uint2 u; } pk;
#pragma unroll
            for (int r = 0; r < 4; ++r) pk.s[r] = f2bf(acc[tm][tn][r]);
            *(uint2*)(pb + (long)b * 512 + cb) = pk.u;
        }
}

// ---------------------------------------------------------------------------
// tail: h[b][c] = relu(128*sum_z Pb[z][b][c] + b1[c]) (bf16, LDS), then
// out[b][o] = h @ W2T + b2. 256 thr = 4 waves; b-tile 16 (grid 256 blocks);
// each wave owns 64 o columns.
__global__ __launch_bounds__(256) void tail_kernel(
    const unsigned short* __restrict__ Pb,     // [4][4096][512] bf16
    const float* __restrict__ b1,              // [512]
    const unsigned short* __restrict__ W2T,    // [256][512] bf16
    const float* __restrict__ b2,              // [256]
    float* __restrict__ out) {                 // [4096][256]
    __shared__ unsigned short hL[16][516];
    __shared__ float b1s[512];
    const int tid = threadIdx.x;
    const int b0 = blockIdx.x * 16;
    b1s[tid] = b1[tid];
    b1s[tid + 256] = b1[tid + 256];
    __syncthreads();

    const unsigned int* Pu = (const unsigned int*)Pb;   // 2 bf16 per uint
#pragma unroll 4
    for (int idx = tid; idx < 16 * 256; idx += 256) {
        int bL = idx >> 8;                      // 0..15
        int cu = idx & 255;                     // uint index; c = 2*cu
        float s0 = 0.f, s1 = 0.f;
#pragma unroll
        for (int z = 0; z < 4; ++z) {
            unsigned int u = Pu[((long)z * 4096 + b0 + bL) * 256 + cu];
            s0 += bf2f((unsigned short)(u & 0xffff));
            s1 += bf2f((unsigned short)(u >> 16));
        }
        int c = cu * 2;
        float v0 = fmaxf(fmaf(128.f, s0, b1s[c]), 0.f);
        float v1 = fmaxf(fmaf(128.f, s1, b1s[c + 1]), 0.f);
        unsigned int pk = (unsigned int)f2bf(v0) | ((unsigned int)f2bf(v1) << 16);
        *(unsigned int*)&hL[bL][c] = pk;
    }
    __syncthreads();

    const int w = tid >> 6, lane = tid & 63;
    const int n16 = lane & 15, quad = lane >> 4;
    const int o0 = w * 64;
    floatx4 acc[4];
#pragma unroll
    for (int tn = 0; tn < 4; ++tn) acc[tn] = (floatx4){0.f, 0.f, 0.f, 0.f};

#pragma unroll 4
    for (int ks = 0; ks < 16; ++ks) {
        short8 Af, Bf[4];
        {
            const unsigned short* p = &hL[n16][ks * 32 + quad * 8];
            union { uint2 u[2]; short8 s; } cvt;
            cvt.u[0] = *(const uint2*)p;
            cvt.u[1] = *(const uint2*)(p + 4);
            Af = cvt.s;
        }
#pragma unroll
        for (int tn = 0; tn < 4; ++tn)
            Bf[tn] = *(const short8*)(W2T + (long)(o0 + tn * 16 + n16) * 512
                                      + ks * 32 + quad * 8);
#pragma unroll
        for (int tn = 0; tn < 4; ++tn)
            acc[tn] = __builtin_amdgcn_mfma_f32_16x16x32_bf16(
                Af, Bf[tn], acc[tn], 0, 0, 0);
    }
#pragma unroll
    for (int tn = 0; tn < 4; ++tn) {
        float bias = b2[o0 + tn * 16 + n16];
#pragma unroll
        for (int r = 0; r < 4; ++r)
            out[(long)(b0 + quad * 4 + r) * 256
                + o0 + tn * 16 + n16] = acc[tn][r] + bias;
    }
}

extern "C" void kernel_launch(void* const* d_in, const int* in_sizes, int n_in,
                              void* d_out, int out_size, void* d_ws, size_t ws_size,
                              hipStream_t stream) {
    const float* x  = (const float*)d_in[0];   // [4096,128]
    const float* W1 = (const float*)d_in[1];   // [16384,512]
    const float* b1 = (const float*)d_in[2];   // [512]
    const float* W2 = (const float*)d_in[3];   // [512,256]
    const float* b2 = (const float*)d_in[4];   // [256]
    float* out = (float*)d_out;                // [4096,256]

    char* ws = (char*)d_ws;
    unsigned short* W1Tp = (unsigned short*)(ws);                 // 16.78 MB
    unsigned short* W2T  = (unsigned short*)(ws + 16777216);      // 0.26 MB
    unsigned short* Pb   = (unsigned short*)(ws + 16777216 + 262144); // 16.78 MB bf16

    pack_w1_kernel<<<dim3(256, 8), 256, 0, stream>>>(W1, W1Tp);
    transpose_cast_kernel<<<dim3(8, 4), 256, 0, stream>>>(W2, W2T, 512, 256);
    gemm1_kernel<<<dim3(16, 8, 4), 256, 0, stream>>>(x, W1Tp, Pb);
    tail_kernel<<<dim3(256), 256, 0, stream>>>(Pb, b1, W2T, b2, out);
}

// Round 9
// 199.880 us; speedup vs baseline: 1.0151x; 1.0151x over previous
//
#include <hip/hip_runtime.h>
#include <hip/hip_bf16.h>

// SO3TensorProductLayer: out = relu(128*(x (x) x) @ W1 + b1) @ W2 + b2
// gemm1 v5 (materialized-B GEMM, fold-free):
//   h[c][b] = sum_K W1T[c][K] * V[K][b],  V[(i,j)][b] = x[b,i]*x[b,j]
// Per 32-wide K-chunk (i fixed, j-window 32): threads compute V-products
// fp32->bf16 into an LDS B-tile; MFMA accumulates directly into acc (pure
// AGPR, no VALU contact -> no VGPR/AGPR straddle, the r8 killer). Chunk
// order (jw outer, i inner) keeps each thread's xj[16] register-resident
// for 32 consecutive chunks. A = W1 packed chunks, global->VGPR.
// Unified reg demand ~105 -> (256,4) fits honestly: 4 blocks/CU.
// Partials bf16 [z][b][c] (r4-proven), tail fuses z-sum+bias+relu+gemm2.

typedef __attribute__((ext_vector_type(8))) short short8;   // 8 bf16
typedef __attribute__((ext_vector_type(4))) float floatx4;  // 4 fp32

__device__ __forceinline__ unsigned short f2bf(float f) {
    union { float f; unsigned int u; } v; v.f = f;
    unsigned int r = v.u + 0x7fffu + ((v.u >> 16) & 1u);   // RNE
    return (unsigned short)(r >> 16);
}
__device__ __forceinline__ float bf2f(unsigned short b) {
    union { unsigned int u; float f; } v; v.u = ((unsigned int)b) << 16;
    return v.f;
}
__device__ __forceinline__ unsigned int pk2bf(float a, float b) {
    float2 p; p.x = a; p.y = b;
    __hip_bfloat162 h = __float22bfloat162_rn(p);
    union { __hip_bfloat162 h; unsigned int u; } cv; cv.h = h;
    return cv.u;
}

// ---------------------------------------------------------------------------
// Pack W1 [16384 K][512 C] fp32 -> W1Tp chunks of 1KB: chunk(c16,kc) holds
// A-fragment for c rows c16*16..+15, K cols kc*32..+31: wave load at
// (chunkBase + lane*16B) gives lane(m=lane&15,quad=lane>>4) the 8 bf16 of
// W1[K=kc*32+quad*8+j][c=c16*16+m].
__global__ __launch_bounds__(256) void pack_w1_kernel(
    const float* __restrict__ W1, unsigned short* __restrict__ W1Tp) {
    __shared__ float tile[64][65];
    const int k0 = blockIdx.x * 64;
    const int c0 = blockIdx.y * 64;
    const int tr = threadIdx.x >> 4;
    const int tc4 = (threadIdx.x & 15) * 4;
#pragma unroll
    for (int p = 0; p < 4; ++p) {
        int k = p * 16 + tr;
        float4 v = *(const float4*)(W1 + (long)(k0 + k) * 512 + c0 + tc4);
        tile[k][tc4 + 0] = v.x; tile[k][tc4 + 1] = v.y;
        tile[k][tc4 + 2] = v.z; tile[k][tc4 + 3] = v.w;
    }
    __syncthreads();
    const int lane = threadIdx.x & 63;
    const int w = threadIdx.x >> 6;
    const int m = lane & 15, quad = lane >> 4;
#pragma unroll
    for (int pass = 0; pass < 2; ++pass) {
        int chunk = w * 2 + pass;              // 0..7
        int kcL = chunk & 1, c16L = chunk >> 1;
        union { unsigned short s[8]; uint4 u; } o;
#pragma unroll
        for (int j = 0; j < 8; ++j)
            o.s[j] = f2bf(tile[kcL * 32 + quad * 8 + j][c16L * 16 + m]);
        long c16g = (c0 >> 4) + c16L;
        long kcg  = (k0 >> 5) + kcL;
        *(uint4*)(W1Tp + (c16g * 512 + kcg) * 512 + lane * 8) = o.u;
    }
}

// in: [R][C] fp32 -> out: [C][R] bf16 (for W2 -> W2T).
__global__ __launch_bounds__(256) void transpose_cast_kernel(
    const float* __restrict__ in, unsigned short* __restrict__ out, int R, int C) {
    __shared__ float tile[64][65];
    const int r0 = blockIdx.x * 64, c0 = blockIdx.y * 64;
    const int tr = threadIdx.x >> 4;
    const int tc4 = (threadIdx.x & 15) * 4;
#pragma unroll
    for (int p = 0; p < 4; ++p) {
        int r = p * 16 + tr;
        float4 v = *(const float4*)(in + (long)(r0 + r) * C + c0 + tc4);
        tile[r][tc4 + 0] = v.x; tile[r][tc4 + 1] = v.y;
        tile[r][tc4 + 2] = v.z; tile[r][tc4 + 3] = v.w;
    }
    __syncthreads();
#pragma unroll
    for (int p = 0; p < 4; ++p) {
        int c = p * 16 + tr;
        union { unsigned short s[4]; uint2 u; } pk;
#pragma unroll
        for (int e = 0; e < 4; ++e) pk.s[e] = f2bf(tile[tc4 + e][c]);
        *(uint2*)(out + (long)(c0 + c) * R + r0 + tc4) = pk.u;
    }
}

// ---------------------------------------------------------------------------
// gemm1 v5: Pb[z][b][c] over i-chunk z. 256 thr = 4 waves, each wave owns a
// b32 quarter (tn=2) x all c64 (tm=4). Block tile c64 x b128, K in 32-chunks
// ordered (jw outer, i inner). grid (32 b, 8 c, 4 z) = 1024 blocks, 4/CU.
__global__ __launch_bounds__(256, 4) void gemm1_kernel(
    const float* __restrict__ x,               // [4096][128]
    const unsigned short* __restrict__ W1Tp,
    unsigned short* __restrict__ Pb) {         // [4][4096][512] bf16
    __shared__ float xiT[128][34];             // [b_local][i_local] fp32
    __shared__ unsigned short Bt[128][40];     // [b_local][k32] bf16, stride 40
    const int tid = threadIdx.x;
    const int b0 = blockIdx.x * 128;
    const int c0 = blockIdx.y * 64;
    const int zi = blockIdx.z;
    const int i0 = zi * 32;

    // stage xiT[b][i] (fold multipliers, fp32), coalesced
    for (int idx = tid; idx < 128 * 32; idx += 256) {
        int bL = idx >> 5, iL = idx & 31;
        xiT[bL][iL] = x[(long)(b0 + bL) * 128 + i0 + iL];
    }
    __syncthreads();

    const int wid = tid >> 6;                  // wave -> b32 quarter
    const int lane = tid & 63;
    const int n16 = lane & 15, quad = lane >> 4;
    const int bLp = tid & 127;                 // product-phase local b
    const int jsub = tid >> 7;                 // 0/1: j-half of the 32-window
    const int c16base = c0 >> 4;

    floatx4 acc[4][2];                         // [tm(c)][tn(b)] - MFMA-only
#pragma unroll
    for (int tm = 0; tm < 4; ++tm)
#pragma unroll
        for (int tn = 0; tn < 2; ++tn) acc[tm][tn] = (floatx4){0.f, 0.f, 0.f, 0.f};

    for (int jw = 0; jw < 4; ++jw) {
        // xj[16] register-resident for this 32-chunk epoch (L2-resident x)
        float xj[16];
        const float* xrow = x + (long)(b0 + bLp) * 128 + jw * 32 + jsub * 16;
#pragma unroll
        for (int e = 0; e < 16; ++e) xj[e] = xrow[e];

        for (int i = 0; i < 32; ++i) {
            // A chunks for this (jw,i), issued early (vmcnt covered by products)
            const int kcg = (i0 + i) * 4 + jw;
            short8 Af0 = *(const short8*)(W1Tp + ((long)(c16base + 0) * 512 + kcg) * 512 + lane * 8);
            short8 Af1 = *(const short8*)(W1Tp + ((long)(c16base + 1) * 512 + kcg) * 512 + lane * 8);
            short8 Af2 = *(const short8*)(W1Tp + ((long)(c16base + 2) * 512 + kcg) * 512 + lane * 8);
            short8 Af3 = *(const short8*)(W1Tp + ((long)(c16base + 3) * 512 + kcg) * 512 + lane * 8);

            // products: V[k][b] = xi*xj, bf16, into Bt (two 16B writes)
            float xi = xiT[bLp][i];
            uint4 w0, w1;
            w0.x = pk2bf(xi * xj[0],  xi * xj[1]);
            w0.y = pk2bf(xi * xj[2],  xi * xj[3]);
            w0.z = pk2bf(xi * xj[4],  xi * xj[5]);
            w0.w = pk2bf(xi * xj[6],  xi * xj[7]);
            w1.x = pk2bf(xi * xj[8],  xi * xj[9]);
            w1.y = pk2bf(xi * xj[10], xi * xj[11]);
            w1.z = pk2bf(xi * xj[12], xi * xj[13]);
            w1.w = pk2bf(xi * xj[14], xi * xj[15]);
            *(uint4*)&Bt[bLp][jsub * 16 + 0] = w0;
            *(uint4*)&Bt[bLp][jsub * 16 + 8] = w1;
            __syncthreads();

            // MFMA phase: B-frags from LDS (reused across 4 tm)
            short8 Bf0 = *(const short8*)&Bt[wid * 32 + n16][quad * 8];
            short8 Bf1 = *(const short8*)&Bt[wid * 32 + 16 + n16][quad * 8];
            acc[0][0] = __builtin_amdgcn_mfma_f32_16x16x32_bf16(Af0, Bf0, acc[0][0], 0, 0, 0);
            acc[0][1] = __builtin_amdgcn_mfma_f32_16x16x32_bf16(Af0, Bf1, acc[0][1], 0, 0, 0);
            acc[1][0] = __builtin_amdgcn_mfma_f32_16x16x32_bf16(Af1, Bf0, acc[1][0], 0, 0, 0);
            acc[1][1] = __builtin_amdgcn_mfma_f32_16x16x32_bf16(Af1, Bf1, acc[1][1], 0, 0, 0);
            acc[2][0] = __builtin_amdgcn_mfma_f32_16x16x32_bf16(Af2, Bf0, acc[2][0], 0, 0, 0);
            acc[2][1] = __builtin_amdgcn_mfma_f32_16x16x32_bf16(Af2, Bf1, acc[2][1], 0, 0, 0);
            acc[3][0] = __builtin_amdgcn_mfma_f32_16x16x32_bf16(Af3, Bf0, acc[3][0], 0, 0, 0);
            acc[3][1] = __builtin_amdgcn_mfma_f32_16x16x32_bf16(Af3, Bf1, acc[3][1], 0, 0, 0);
            __syncthreads();                   // Bt reads done before overwrite
        }
    }

    // epilogue: bf16 partial in [z][b][c]; lane owns 4 c-consecutive per (tm,tn)
    unsigned short* pb = Pb + (long)zi * (4096L * 512);
#pragma unroll
    for (int tm = 0; tm < 4; ++tm)
#pragma unroll
        for (int tn = 0; tn < 2; ++tn) {
            int b = b0 + wid * 32 + tn * 16 + n16;
            int cb = c0 + tm * 16 + quad * 4;
            union { unsigned short s[4]; uint2 u; } pk;
#pragma unroll
            for (int r = 0; r < 4; ++r) pk.s[r] = f2bf(acc[tm][tn][r]);
            *(uint2*)(pb + (long)b * 512 + cb) = pk.u;
        }
}

// ---------------------------------------------------------------------------
// tail: h[b][c] = relu(128*sum_z Pb[z][b][c] + b1[c]) (bf16, LDS), then
// out[b][o] = h @ W2T + b2. 256 thr = 4 waves; b-tile 16 (grid 256 blocks).
__global__ __launch_bounds__(256) void tail_kernel(
    const unsigned short* __restrict__ Pb,     // [4][4096][512] bf16
    const float* __restrict__ b1,              // [512]
    const unsigned short* __restrict__ W2T,    // [256][512] bf16
    const float* __restrict__ b2,              // [256]
    float* __restrict__ out) {                 // [4096][256]
    __shared__ unsigned short hL[16][516];
    __shared__ float b1s[512];
    const int tid = threadIdx.x;
    const int b0 = blockIdx.x * 16;
    b1s[tid] = b1[tid];
    b1s[tid + 256] = b1[tid + 256];
    __syncthreads();

    const unsigned int* Pu = (const unsigned int*)Pb;   // 2 bf16 per uint
#pragma unroll 4
    for (int idx = tid; idx < 16 * 256; idx += 256) {
        int bL = idx >> 8;                      // 0..15
        int cu = idx & 255;                     // uint index; c = 2*cu
        float s0 = 0.f, s1 = 0.f;
#pragma unroll
        for (int z = 0; z < 4; ++z) {
            unsigned int u = Pu[((long)z * 4096 + b0 + bL) * 256 + cu];
            s0 += bf2f((unsigned short)(u & 0xffff));
            s1 += bf2f((unsigned short)(u >> 16));
        }
        int c = cu * 2;
        float v0 = fmaxf(fmaf(128.f, s0, b1s[c]), 0.f);
        float v1 = fmaxf(fmaf(128.f, s1, b1s[c + 1]), 0.f);
        unsigned int pk = (unsigned int)f2bf(v0) | ((unsigned int)f2bf(v1) << 16);
        *(unsigned int*)&hL[bL][c] = pk;
    }
    __syncthreads();

    const int w = tid >> 6, lane = tid & 63;
    const int n16 = lane & 15, quad = lane >> 4;
    const int o0 = w * 64;
    floatx4 acc[4];
#pragma unroll
    for (int tn = 0; tn < 4; ++tn) acc[tn] = (floatx4){0.f, 0.f, 0.f, 0.f};

#pragma unroll 4
    for (int ks = 0; ks < 16; ++ks) {
        short8 Af, Bf[4];
        {
            const unsigned short* p = &hL[n16][ks * 32 + quad * 8];
            union { uint2 u[2]; short8 s; } cvt;
            cvt.u[0] = *(const uint2*)p;
            cvt.u[1] = *(const uint2*)(p + 4);
            Af = cvt.s;
        }
#pragma unroll
        for (int tn = 0; tn < 4; ++tn)
            Bf[tn] = *(const short8*)(W2T + (long)(o0 + tn * 16 + n16) * 512
                                      + ks * 32 + quad * 8);
#pragma unroll
        for (int tn = 0; tn < 4; ++tn)
            acc[tn] = __builtin_amdgcn_mfma_f32_16x16x32_bf16(
                Af, Bf[tn], acc[tn], 0, 0, 0);
    }
#pragma unroll
    for (int tn = 0; tn < 4; ++tn) {
        float bias = b2[o0 + tn * 16 + n16];
#pragma unroll
        for (int r = 0; r < 4; ++r)
            out[(long)(b0 + quad * 4 + r) * 256
                + o0 + tn * 16 + n16] = acc[tn][r] + bias;
    }
}

extern "C" void kernel_launch(void* const* d_in, const int* in_sizes, int n_in,
                              void* d_out, int out_size, void* d_ws, size_t ws_size,
                              hipStream_t stream) {
    const float* x  = (const float*)d_in[0];   // [4096,128]
    const float* W1 = (const float*)d_in[1];   // [16384,512]
    const float* b1 = (const float*)d_in[2];   // [512]
    const float* W2 = (const float*)d_in[3];   // [512,256]
    const float* b2 = (const float*)d_in[4];   // [256]
    float* out = (float*)d_out;                // [4096,256]

    char* ws = (char*)d_ws;
    unsigned short* W1Tp = (unsigned short*)(ws);                 // 16.78 MB
    unsigned short* W2T  = (unsigned short*)(ws + 16777216);      // 0.26 MB
    unsigned short* Pb   = (unsigned short*)(ws + 16777216 + 262144); // 16.78 MB bf16

    pack_w1_kernel<<<dim3(256, 8), 256, 0, stream>>>(W1, W1Tp);
    transpose_cast_kernel<<<dim3(8, 4), 256, 0, stream>>>(W2, W2T, 512, 256);
    gemm1_kernel<<<dim3(32, 8, 4), 256, 0, stream>>>(x, W1Tp, Pb);
    tail_kernel<<<dim3(256), 256, 0, stream>>>(Pb, b1, W2T, b2, out);
}

// Round 10
// 188.541 us; speedup vs baseline: 1.0762x; 1.0601x over previous
//
#include <hip/hip_runtime.h>
#include <hip/hip_bf16.h>

// SO3TensorProductLayer: out = relu(128*(x (x) x) @ W1 + b1) @ W2 + b2
// SYMMETRY (r10): x_i x_j symmetric -> h[c][b] = sum_{d,i} S[(d,i)][c] * x_i x_{(i+d)%128}
// with S[(d,i)] = W1[(i,j)] + W1[(j,i)] (d>0), W1[(i,i)] (d=0), j=(i+d)%128.
// d=0..64 covers each unordered pair exactly once -> K = 8448 (4 iw x 66 d x 32,
// incl. zero pad at d=65 and d=64/i>=64): HALF the FLOP and staging of r2..r9.
// gemm1: per epoch (d-pair, BK=64): threads build B-tile products into LDS
// (rotated strip = contiguous bf16 run from xF), barrier, 16 MFMAs/wave from
// prefetched Af (issued at epoch top; ~350cyc products cover L2 latency).
// No launch-bounds cap (r5/r7 spill trap); acc pure-MFMA (no fold VALU).
// All LDS strides bank-verified: xF 67 dwords, Bt 72 u16.

typedef __attribute__((ext_vector_type(8))) short short8;   // 8 bf16
typedef __attribute__((ext_vector_type(4))) float floatx4;  // 4 fp32

__device__ __forceinline__ unsigned short f2bf(float f) {
    union { float f; unsigned int u; } v; v.f = f;
    unsigned int r = v.u + 0x7fffu + ((v.u >> 16) & 1u);   // RNE
    return (unsigned short)(r >> 16);
}
__device__ __forceinline__ float bf2f(unsigned short b) {
    union { unsigned int u; float f; } v; v.u = ((unsigned int)b) << 16;
    return v.f;
}
__device__ __forceinline__ unsigned int pk2bf(float a, float b) {
    float2 p; p.x = a; p.y = b;
    __hip_bfloat162 h = __float22bfloat162_rn(p);
    union { __hip_bfloat162 h; unsigned int u; } cv; cv.h = h;
    return cv.u;
}
__device__ __forceinline__ float bflo(unsigned int w) {
    union { unsigned int u; float f; } v; v.u = w << 16; return v.f;
}
__device__ __forceinline__ float bfhi(unsigned int w) {
    union { unsigned int u; float f; } v; v.u = w & 0xffff0000u; return v.f;
}

// ---------------------------------------------------------------------------
// pack_s: S symmetric-packed into MFMA A-fragment chunks of 1KB.
// Chunk (c16, kc), kc = iw*66 + d: lane(m,quad) elem e -> S for
// c = c16*16+m, i = iw*32+quad*8+e, j = (i+d)%128.
// grid (264 kc, 8), 256 thr (4 c16 per block).
__global__ __launch_bounds__(256) void pack_s_kernel(
    const float* __restrict__ W1, unsigned short* __restrict__ Sp) {
    const int kc = blockIdx.x;             // 0..263
    const int iw = kc / 66;
    const int d  = kc - iw * 66;           // 0..65
    const int c16 = blockIdx.y * 4 + (threadIdx.x >> 6);
    const int lane = threadIdx.x & 63;
    const int m = lane & 15, quad = lane >> 4;
    const int c = c16 * 16 + m;
    union { unsigned short s[8]; uint4 u; } o;
#pragma unroll
    for (int e = 0; e < 8; ++e) {
        int i = iw * 32 + quad * 8 + e;
        float val;
        if (d == 0) {
            val = W1[((long)i * 128 + i) * 512 + c];
        } else if (d >= 65 || (d == 64 && i >= 64)) {
            val = 0.f;
        } else {
            int j = (i + d) & 127;
            val = W1[((long)i * 128 + j) * 512 + c]
                + W1[((long)j * 128 + i) * 512 + c];
        }
        o.s[e] = f2bf(val);
    }
    *(uint4*)(Sp + ((long)c16 * 264 + kc) * 512 + lane * 8) = o.u;
}

// in: [R][C] fp32 -> out: [C][R] bf16 (for W2 -> W2T).
__global__ __launch_bounds__(256) void transpose_cast_kernel(
    const float* __restrict__ in, unsigned short* __restrict__ out, int R, int C) {
    __shared__ float tile[64][65];
    const int r0 = blockIdx.x * 64, c0 = blockIdx.y * 64;
    const int tr = threadIdx.x >> 4;
    const int tc4 = (threadIdx.x & 15) * 4;
#pragma unroll
    for (int p = 0; p < 4; ++p) {
        int r = p * 16 + tr;
        float4 v = *(const float4*)(in + (long)(r0 + r) * C + c0 + tc4);
        tile[r][tc4 + 0] = v.x; tile[r][tc4 + 1] = v.y;
        tile[r][tc4 + 2] = v.z; tile[r][tc4 + 3] = v.w;
    }
    __syncthreads();
#pragma unroll
    for (int p = 0; p < 4; ++p) {
        int c = p * 16 + tr;
        union { unsigned short s[4]; uint2 u; } pk;
#pragma unroll
        for (int e = 0; e < 4; ++e) pk.s[e] = f2bf(tile[tc4 + e][c]);
        *(uint2*)(out + (long)(c0 + c) * R + r0 + tc4) = pk.u;
    }
}

// ---------------------------------------------------------------------------
// gemm1 v6 (symmetric): Pb[z][b][c] bf16, z splits iw-pairs. Block 256 thr,
// tile c64 x b128; 4 waves each c64 x b32 (tm=4, tn=2). grid (32 b, 8 c, 2 z)
// = 512 blocks = 2/CU (LDS ~53 KB). Epoch = d-pair (BK=64): products ->
// barrier -> 16 MFMA -> barrier; 132 epochs/block.
__global__ __launch_bounds__(256) void gemm1_kernel(
    const float* __restrict__ x,               // [4096][128]
    const unsigned short* __restrict__ Sp,     // packed S chunks
    unsigned short* __restrict__ Pb) {         // [2][4096][512] bf16
    __shared__ unsigned int xF[128][67];       // bf16 pairs; dwords 0..63 used
    __shared__ unsigned short Bt[128][72];     // [b][k64] products
    const int tid = threadIdx.x;
    const int b0 = blockIdx.x * 128;
    const int c0 = blockIdx.y * 64;
    const int z  = blockIdx.z;

    // stage xF[b][i] (bf16-packed x rows)
    for (int n = tid; n < 128 * 64; n += 256) {
        int row = n >> 6, dcol = n & 63;
        const float* xp = x + (long)(b0 + row) * 128 + dcol * 2;
        xF[row][dcol] = pk2bf(xp[0], xp[1]);
    }
    __syncthreads();

    const int wid = tid >> 6;
    const int lane = tid & 63;
    const int n16 = lane & 15, quad = lane >> 4;
    const int bL = tid & 127;                  // product-phase b row
    const int h2 = tid >> 7;                   // which d of the pair
    const int c16base = c0 >> 4;

    floatx4 acc[4][2];
#pragma unroll
    for (int tm = 0; tm < 4; ++tm)
#pragma unroll
        for (int tn = 0; tn < 2; ++tn) acc[tm][tn] = (floatx4){0.f, 0.f, 0.f, 0.f};

    for (int iwL = 0; iwL < 2; ++iwL) {
        const int iw = z * 2 + iwL;
        // xi window (fp32, exact operand) register-resident for 33 epochs
        float xi[32];
        const float* xip = x + (long)(b0 + bL) * 128 + iw * 32;
#pragma unroll
        for (int t = 0; t < 32; ++t) xi[t] = xip[t];

        for (int ep = 0; ep < 33; ++ep) {
            const int d0 = ep * 2;
            const int d = d0 + h2;
            // Af prefetch (8 x dwordx4); consumed after products+barrier
            short8 Af[4][2];
#pragma unroll
            for (int tm = 0; tm < 4; ++tm)
#pragma unroll
                for (int sub = 0; sub < 2; ++sub)
                    Af[tm][sub] = *(const short8*)(Sp
                        + ((long)(c16base + tm) * 264 + (long)iw * 66 + d0 + sub) * 512
                        + lane * 8);

            // products: rot strip = xF[bL][s..s+31 mod 128], contiguous
            const int s = (iw * 32 + d) & 127;
            const int sd = s >> 1;
            unsigned int u[17];
#pragma unroll
            for (int q = 0; q < 17; ++q) u[q] = xF[bL][(sd + q) & 63];
            float rot[32];
            if (s & 1) {                       // wave-uniform branch
#pragma unroll
                for (int t = 0; t < 32; ++t) {
                    unsigned int w = u[(t + 1) >> 1];
                    rot[t] = ((t & 1) ? bflo(w) : bfhi(w));
                }
            } else {
#pragma unroll
                for (int t = 0; t < 32; ++t) {
                    unsigned int w = u[t >> 1];
                    rot[t] = ((t & 1) ? bfhi(w) : bflo(w));
                }
            }
            unsigned short* bw = &Bt[bL][h2 * 32];
#pragma unroll
            for (int g8 = 0; g8 < 4; ++g8) {
                uint4 wv;
                wv.x = pk2bf(xi[g8*8+0]*rot[g8*8+0], xi[g8*8+1]*rot[g8*8+1]);
                wv.y = pk2bf(xi[g8*8+2]*rot[g8*8+2], xi[g8*8+3]*rot[g8*8+3]);
                wv.z = pk2bf(xi[g8*8+4]*rot[g8*8+4], xi[g8*8+5]*rot[g8*8+5]);
                wv.w = pk2bf(xi[g8*8+6]*rot[g8*8+6], xi[g8*8+7]*rot[g8*8+7]);
                *(uint4*)(bw + g8 * 8) = wv;
            }
            __syncthreads();

            // MFMA phase: 16 per wave
#pragma unroll
            for (int sub = 0; sub < 2; ++sub) {
                short8 Bf0 = *(const short8*)&Bt[wid * 32 + n16][sub * 32 + quad * 8];
                short8 Bf1 = *(const short8*)&Bt[wid * 32 + 16 + n16][sub * 32 + quad * 8];
#pragma unroll
                for (int tm = 0; tm < 4; ++tm) {
                    acc[tm][0] = __builtin_amdgcn_mfma_f32_16x16x32_bf16(
                        Af[tm][sub], Bf0, acc[tm][0], 0, 0, 0);
                    acc[tm][1] = __builtin_amdgcn_mfma_f32_16x16x32_bf16(
                        Af[tm][sub], Bf1, acc[tm][1], 0, 0, 0);
                }
            }
            __syncthreads();
        }
    }

    // epilogue: bf16 partial [z][b][c]; lane owns 4 c-consecutive per (tm,tn)
    unsigned short* pb = Pb + (long)z * (4096L * 512);
#pragma unroll
    for (int tm = 0; tm < 4; ++tm)
#pragma unroll
        for (int tn = 0; tn < 2; ++tn) {
            int b = b0 + wid * 32 + tn * 16 + n16;
            int cb = c0 + tm * 16 + quad * 4;
            union { unsigned short s[4]; uint2 u; } pk;
#pragma unroll
            for (int r = 0; r < 4; ++r) pk.s[r] = f2bf(acc[tm][tn][r]);
            *(uint2*)(pb + (long)b * 512 + cb) = pk.u;
        }
}

// ---------------------------------------------------------------------------
// tail: h[b][c] = relu(128*sum_z Pb[z][b][c] + b1[c]) (bf16, LDS), then
// out[b][o] = h @ W2T + b2. 256 thr = 4 waves; b-tile 16 (grid 256 blocks).
__global__ __launch_bounds__(256) void tail_kernel(
    const unsigned short* __restrict__ Pb,     // [2][4096][512] bf16
    const float* __restrict__ b1,              // [512]
    const unsigned short* __restrict__ W2T,    // [256][512] bf16
    const float* __restrict__ b2,              // [256]
    float* __restrict__ out) {                 // [4096][256]
    __shared__ unsigned short hL[16][516];
    __shared__ float b1s[512];
    const int tid = threadIdx.x;
    const int b0 = blockIdx.x * 16;
    b1s[tid] = b1[tid];
    b1s[tid + 256] = b1[tid + 256];
    __syncthreads();

    const unsigned int* Pu = (const unsigned int*)Pb;   // 2 bf16 per uint
#pragma unroll 4
    for (int idx = tid; idx < 16 * 256; idx += 256) {
        int bL = idx >> 8;                      // 0..15
        int cu = idx & 255;                     // uint index; c = 2*cu
        float s0 = 0.f, s1 = 0.f;
#pragma unroll
        for (int zz = 0; zz < 2; ++zz) {
            unsigned int u = Pu[((long)zz * 4096 + b0 + bL) * 256 + cu];
            s0 += bf2f((unsigned short)(u & 0xffff));
            s1 += bf2f((unsigned short)(u >> 16));
        }
        int c = cu * 2;
        float v0 = fmaxf(fmaf(128.f, s0, b1s[c]), 0.f);
        float v1 = fmaxf(fmaf(128.f, s1, b1s[c + 1]), 0.f);
        unsigned int pk = (unsigned int)f2bf(v0) | ((unsigned int)f2bf(v1) << 16);
        *(unsigned int*)&hL[bL][c] = pk;
    }
    __syncthreads();

    const int w = tid >> 6, lane = tid & 63;
    const int n16 = lane & 15, quad = lane >> 4;
    const int o0 = w * 64;
    floatx4 acc[4];
#pragma unroll
    for (int tn = 0; tn < 4; ++tn) acc[tn] = (floatx4){0.f, 0.f, 0.f, 0.f};

#pragma unroll 4
    for (int ks = 0; ks < 16; ++ks) {
        short8 Af, Bf[4];
        {
            const unsigned short* p = &hL[n16][ks * 32 + quad * 8];
            union { uint2 u[2]; short8 s; } cvt;
            cvt.u[0] = *(const uint2*)p;
            cvt.u[1] = *(const uint2*)(p + 4);
            Af = cvt.s;
        }
#pragma unroll
        for (int tn = 0; tn < 4; ++tn)
            Bf[tn] = *(const short8*)(W2T + (long)(o0 + tn * 16 + n16) * 512
                                      + ks * 32 + quad * 8);
#pragma unroll
        for (int tn = 0; tn < 4; ++tn)
            acc[tn] = __builtin_amdgcn_mfma_f32_16x16x32_bf16(
                Af, Bf[tn], acc[tn], 0, 0, 0);
    }
#pragma unroll
    for (int tn = 0; tn < 4; ++tn) {
        float bias = b2[o0 + tn * 16 + n16];
#pragma unroll
        for (int r = 0; r < 4; ++r)
            out[(long)(b0 + quad * 4 + r) * 256
                + o0 + tn * 16 + n16] = acc[tn][r] + bias;
    }
}

extern "C" void kernel_launch(void* const* d_in, const int* in_sizes, int n_in,
                              void* d_out, int out_size, void* d_ws, size_t ws_size,
                              hipStream_t stream) {
    const float* x  = (const float*)d_in[0];   // [4096,128]
    const float* W1 = (const float*)d_in[1];   // [16384,512]
    const float* b1 = (const float*)d_in[2];   // [512]
    const float* W2 = (const float*)d_in[3];   // [512,256]
    const float* b2 = (const float*)d_in[4];   // [256]
    float* out = (float*)d_out;                // [4096,256]

    char* ws = (char*)d_ws;
    unsigned short* Sp  = (unsigned short*)(ws);                  // 8.65 MB
    unsigned short* W2T = (unsigned short*)(ws + 8650752);        // 0.26 MB
    unsigned short* Pb  = (unsigned short*)(ws + 8650752 + 262144); // 8.39 MB

    pack_s_kernel<<<dim3(264, 8), 256, 0, stream>>>(W1, Sp);
    transpose_cast_kernel<<<dim3(8, 4), 256, 0, stream>>>(W2, W2T, 512, 256);
    gemm1_kernel<<<dim3(32, 8, 2), 256, 0, stream>>>(x, Sp, Pb);
    tail_kernel<<<dim3(256), 256, 0, stream>>>(Pb, b1, W2T, b2, out);
}